// Round 6
// baseline (7011.700 us; speedup 1.0000x reference)
//
#include <hip/hip_runtime.h>
#include <stdint.h>
#include <math.h>

// Replicate jax.random threefry2x32 exactly (jax_threefry_partitionable=True).
#define PARTITIONABLE 1

namespace {

constexpr int kB = 4096;
constexpr int kN = 256;
constexpr int kSweeps = 200;
constexpr int kSamp = 8;                 // samples per block (2 halves of 4)
constexpr int kG = 4;                    // samples per thread
constexpr int kBlocks = kB / kSamp;      // 512 blocks of 512 threads

struct K2 { uint32_t a, b; };

__host__ __device__ constexpr uint32_t crotl(uint32_t x, int d) {
  return (x << d) | (x >> (32 - d));
}

// Threefry-2x32, 20 rounds, exactly as jax/_src/prng.py
__host__ __device__ constexpr K2 ctf(uint32_t k0, uint32_t k1, uint32_t c0, uint32_t c1) {
  uint32_t ks0 = k0, ks1 = k1, ks2 = k0 ^ k1 ^ 0x1BD11BDAu;
  uint32_t x0 = c0 + ks0, x1 = c1 + ks1;
  const int r0[4] = {13, 15, 26, 6};
  const int r1[4] = {17, 29, 16, 24};
  for (int i = 0; i < 4; ++i) { x0 += x1; x1 = crotl(x1, r0[i]); x1 ^= x0; }
  x0 += ks1; x1 += ks2 + 1u;
  for (int i = 0; i < 4; ++i) { x0 += x1; x1 = crotl(x1, r1[i]); x1 ^= x0; }
  x0 += ks2; x1 += ks0 + 2u;
  for (int i = 0; i < 4; ++i) { x0 += x1; x1 = crotl(x1, r0[i]); x1 ^= x0; }
  x0 += ks0; x1 += ks1 + 3u;
  for (int i = 0; i < 4; ++i) { x0 += x1; x1 = crotl(x1, r1[i]); x1 ^= x0; }
  x0 += ks1; x1 += ks2 + 4u;
  for (int i = 0; i < 4; ++i) { x0 += x1; x1 = crotl(x1, r0[i]); x1 ^= x0; }
  x0 += ks2; x1 += ks0 + 5u;
  return K2{x0, x1};
}

struct KeyTable {
  uint32_t s0k[2];               // key for initial spins (k0)
  uint32_t sk[kSweeps][4];       // per sweep: k1a,k1b (accept), k2a,k2b (mask)
};

constexpr KeyTable make_keys() {
  KeyTable t{};
  K2 root{0u, 42u};              // jax.random.key(42) -> (hi=0, lo=42)
#if PARTITIONABLE
  K2 k0 = ctf(root.a, root.b, 0u, 0u);
  K2 kl = ctf(root.a, root.b, 0u, 1u);
#else
  K2 p0 = ctf(root.a, root.b, 0u, 2u);
  K2 p1 = ctf(root.a, root.b, 1u, 3u);
  K2 k0{p0.a, p1.a};
  K2 kl{p0.b, p1.b};
#endif
  t.s0k[0] = k0.a; t.s0k[1] = k0.b;
  K2 k = kl;
  for (int s = 0; s < kSweeps; ++s) {
#if PARTITIONABLE
    K2 kn = ctf(k.a, k.b, 0u, 0u);
    K2 k1 = ctf(k.a, k.b, 0u, 1u);
    K2 k2 = ctf(k.a, k.b, 0u, 2u);
#else
    K2 q0 = ctf(k.a, k.b, 0u, 3u);
    K2 q1 = ctf(k.a, k.b, 1u, 4u);
    K2 q2 = ctf(k.a, k.b, 2u, 5u);
    K2 kn{q0.a, q1.a};
    K2 k1{q2.a, q0.b};
    K2 k2{q1.b, q2.b};
#endif
    t.sk[s][0] = k1.a; t.sk[s][1] = k1.b;
    t.sk[s][2] = k2.a; t.sk[s][3] = k2.b;
    k = kn;
  }
  return t;
}

__constant__ KeyTable g_keys = make_keys();

__device__ __forceinline__ uint32_t rng_bits32(uint32_t ka, uint32_t kb, uint32_t m) {
#if PARTITIONABLE
  K2 r = ctf(ka, kb, 0u, m);
  return r.a ^ r.b;
#else
  constexpr uint32_t H = (uint32_t)(kB * kN / 2);
  uint32_t p = (m < H) ? m : (m - H);
  K2 r = ctf(ka, kb, p, p + H);
  return (m < H) ? r.a : r.b;
#endif
}

__device__ __forceinline__ float bits_to_uniform(uint32_t bits) {
  // jax: bitcast(bits >> 9 | 0x3f800000) - 1.0
  return __uint_as_float((bits >> 9) | 0x3f800000u) - 1.0f;
}

__global__ void prep_kernel(const float* __restrict__ gamma,
                            float* __restrict__ jsym,
                            float* __restrict__ betas) {
  int e = blockIdx.x * blockDim.x + threadIdx.x;   // 0..65535
  int i = e / kN, j = e % kN;
  float v = 0.0f;
  if (i < j) v = gamma[i * kN + j];
  else if (i > j) v = gamma[j * kN + i];
  jsym[e] = v;
  if (e < kSweeps) {
    double l0 = log(0.1), l1 = log(5.0);
    betas[e] = (float)exp(l0 + (l1 - l0) * (double)e / (double)(kSweeps - 1));
  }
}

// One VALU op per element: f32 fma with the f16 spin operand converted in-op.
// Conversion of +-1.0h to f32 is exact, then fp32 fma -> bit-identical to
// fmaf(+-1.0f, J, acc). op_sel picks lo/hi half of the packed u32.
#define FMIX_LO(a, w, j)                                                      \
  asm("v_fma_mix_f32 %0, %1, %2, %0 op_sel:[0,0,0] op_sel_hi:[1,0,0]"         \
      : "+v"(a) : "v"(w), "v"(j))
#define FMIX_HI(a, w, j)                                                      \
  asm("v_fma_mix_f32 %0, %1, %2, %0 op_sel:[1,0,0] op_sel_hi:[1,0,0]"         \
      : "+v"(a) : "v"(w), "v"(j))

// Exact matvec: acc[g] += sum_j s[g][j] * Jrow[j], j ascending, fp32 chain.
// Spins are fp16 (+-1.0h) in LDS: one ds_read_b128 = 8 spins.
// Software-pipelined A/B (chunk = 8 j's, 32 chunks), rolled 15-iter loop.
// NOTE: keep this exact structure (round-3 codegen, pipelined, VGPR~68) and
// do NOT add a min-waves launch-bounds hint: the occupancy-driven scheduler
// then drops the windows and serializes loads (rounds 4/5, VGPR 44).
__device__ __forceinline__ void matvec_h(const unsigned short* __restrict__ sh,
                                         const float4* __restrict__ jrow4,
                                         float (&acc)[kG]) {
#define LDSP(g, c) (*(const uint4*)(sh + (g) * kN + (c) * 8))
#define CONSUME(SP, J0, J1)                                                   \
  _Pragma("unroll")                                                           \
  for (int g = 0; g < kG; ++g) {                                              \
    FMIX_LO(acc[g], SP[g].x, J0.x); FMIX_HI(acc[g], SP[g].x, J0.y);           \
    FMIX_LO(acc[g], SP[g].y, J0.z); FMIX_HI(acc[g], SP[g].y, J0.w);           \
    FMIX_LO(acc[g], SP[g].z, J1.x); FMIX_HI(acc[g], SP[g].z, J1.y);           \
    FMIX_LO(acc[g], SP[g].w, J1.z); FMIX_HI(acc[g], SP[g].w, J1.w);           \
  }

  uint4 A[kG], B[kG];
  float4 jA0, jA1, jB0, jB1;
#pragma unroll
  for (int g = 0; g < kG; ++g) A[g] = LDSP(g, 0);
  jA0 = jrow4[0]; jA1 = jrow4[1];

#pragma unroll 1
  for (int k = 0; k < 15; ++k) {
    const int c = 2 * k;
    // body 1: prefetch chunk c+1 -> B, consume chunk c (A)
#pragma unroll
    for (int g = 0; g < kG; ++g) B[g] = LDSP(g, c + 1);
    jB0 = jrow4[2 * c + 2]; jB1 = jrow4[2 * c + 3];
    CONSUME(A, jA0, jA1)
    // body 2: prefetch chunk c+2 -> A, consume chunk c+1 (B)
#pragma unroll
    for (int g = 0; g < kG; ++g) A[g] = LDSP(g, c + 2);
    jA0 = jrow4[2 * c + 4]; jA1 = jrow4[2 * c + 5];
    CONSUME(B, jB0, jB1)
  }
  // tail: consume chunk 30 (A) while prefetching 31 -> B, then consume 31
#pragma unroll
  for (int g = 0; g < kG; ++g) B[g] = LDSP(g, 31);
  jB0 = jrow4[62]; jB1 = jrow4[63];
  CONSUME(A, jA0, jA1)
  CONSUME(B, jB0, jB1)
#undef LDSP
#undef CONSUME
}

__global__ __launch_bounds__(512) void anneal_kernel(
    const float* __restrict__ thetas, const float* __restrict__ jsym,
    const float* __restrict__ betas, float* __restrict__ out) {
  // fp16 spins (+1.0h=0x3C00, -1.0h=0xBC00), double-buffered: 8 KiB
  __shared__ __align__(16) unsigned short sh_h[2][kSamp][kN];
  __shared__ float sh_red[kSamp][4];

  const int tid = threadIdx.x;
  const int i = tid & (kN - 1);        // spin index (row of Jsym)
  const int h = tid >> 8;              // half: 0 -> samples 0..3, 1 -> 4..7
  const int gb = h * kG;               // first sample of this half
  const int b0 = blockIdx.x * kSamp;   // first sample of this block
  const int lane = tid & 63;
  const int w4 = (tid >> 6) & 3;       // wave index within the half

  float th[kG], sreg[kG];
#pragma unroll
  for (int g = 0; g < kG; ++g) th[g] = thetas[(b0 + gb + g) * kN + i];

  // s0 = where(bernoulli(k0, 0.5), 1, -1) ; bernoulli = uniform < 0.5
#pragma unroll
  for (int g = 0; g < kG; ++g) {
    uint32_t m = (uint32_t)((b0 + gb + g) * kN + i);
    float u = bits_to_uniform(rng_bits32(g_keys.s0k[0], g_keys.s0k[1], m));
    sreg[g] = (u < 0.5f) ? 1.0f : -1.0f;
    sh_h[0][gb + g][i] = (sreg[g] < 0.0f) ? (unsigned short)0xBC00
                                          : (unsigned short)0x3C00;
  }
  __syncthreads();

  // row i of Jsym; by symmetry local_i = sum_j Jsym[i][j] * s[j]
  // halves share the same jrow -> L1 reuse; 2 blocks/CU keeps L2 J traffic
  // at ~2 row-set reads per CU per sweep
  const float4* __restrict__ jrow4 = (const float4*)(jsym + i * kN);
  int cur = 0;

#pragma unroll 1
  for (int t = 0; t < kSweeps; ++t) {
    const float beta = betas[t];

    // RNG first: independent of spins -> schedulable into matvec load gaps
    const uint32_t k1a = g_keys.sk[t][0], k1b = g_keys.sk[t][1];
    const uint32_t k2a = g_keys.sk[t][2], k2b = g_keys.sk[t][3];
    float u1f[kG];
    uint32_t msk[kG];
#pragma unroll
    for (int g = 0; g < kG; ++g) {
      uint32_t m = (uint32_t)((b0 + gb + g) * kN + i);
      uint32_t b1 = rng_bits32(k1a, k1b, m);
      uint32_t b2 = rng_bits32(k2a, k2b, m);
      u1f[g] = bits_to_uniform(b1);
      msk[g] = b2 >> 31;               // u2 < 0.5  <=>  bit31 == 0
    }

    float acc[kG];
#pragma unroll
    for (int g = 0; g < kG; ++g) acc[g] = 0.0f;
    matvec_h(&sh_h[cur][gb][0], jrow4, acc);

    const int nxt = cur ^ 1;
#pragma unroll
    for (int g = 0; g < kG; ++g) {
      float s = sreg[g];
      float local = th[g] + acc[g];
      float dE = -2.0f * s * local;    // exact: (-2*s) is a power of two
      float pr = expf(-beta * dE);
      if ((u1f[g] < pr) && (msk[g] == 0u)) s = -s;   // accept & mask
      sreg[g] = s;
      sh_h[nxt][gb + g][i] = (s < 0.0f) ? (unsigned short)0xBC00
                                        : (unsigned short)0x3C00;
    }
    __syncthreads();   // nxt-buffer writes visible before next sweep reads
    cur = nxt;
  }

  // E_b = sum_i s_i*theta_i + 0.5 * sum_i s_i * (Jsym s)_i
  {
    float acc[kG];
#pragma unroll
    for (int g = 0; g < kG; ++g) acc[g] = 0.0f;
    matvec_h(&sh_h[cur][gb][0], jrow4, acc);

#pragma unroll
    for (int g = 0; g < kG; ++g) {
      float v = sreg[g] * th[g] + 0.5f * (sreg[g] * acc[g]);
#pragma unroll
      for (int off = 32; off > 0; off >>= 1) v += __shfl_down(v, off);
      if (lane == 0) sh_red[gb + g][w4] = v;
    }
    __syncthreads();
    if (tid < kSamp) {
      int g = tid;
      out[b0 + g] = sh_red[g][0] + sh_red[g][1] + sh_red[g][2] + sh_red[g][3];
    }
  }
}

}  // namespace

extern "C" void kernel_launch(void* const* d_in, const int* in_sizes, int n_in,
                              void* d_out, int out_size, void* d_ws, size_t ws_size,
                              hipStream_t stream) {
  const float* thetas = (const float*)d_in[0];   // [4096, 256]
  const float* gamma  = (const float*)d_in[1];   // [256, 256]
  float* jsym  = (float*)d_ws;                              // 256 KiB
  float* betas = (float*)((char*)d_ws + kN * kN * sizeof(float));

  hipLaunchKernelGGL(prep_kernel, dim3(kN), dim3(kN), 0, stream, gamma, jsym, betas);
  hipLaunchKernelGGL(anneal_kernel, dim3(kBlocks), dim3(512), 0, stream,
                     thetas, jsym, betas, (float*)d_out);
}

// Round 7
// 3205.596 us; speedup vs baseline: 2.1873x; 2.1873x over previous
//
#include <hip/hip_runtime.h>
#include <stdint.h>
#include <math.h>

// Replicate jax.random threefry2x32 exactly (jax_threefry_partitionable=True).
#define PARTITIONABLE 1

namespace {

constexpr int kB = 4096;
constexpr int kN = 256;
constexpr int kSweeps = 200;
constexpr int kSamp = 8;                 // samples per block
constexpr int kBlocks = kB / kSamp;      // 512 blocks of 512 threads
// block = 4 consumer waves (tid<256, matvec+flip) + 4 producer waves
// (tid>=256, next sweep's threefry) -> overlap via TLP, 1 barrier/sweep.

struct K2 { uint32_t a, b; };

__host__ __device__ constexpr uint32_t crotl(uint32_t x, int d) {
  return (x << d) | (x >> (32 - d));
}

// Threefry-2x32, 20 rounds, exactly as jax/_src/prng.py
__host__ __device__ constexpr K2 ctf(uint32_t k0, uint32_t k1, uint32_t c0, uint32_t c1) {
  uint32_t ks0 = k0, ks1 = k1, ks2 = k0 ^ k1 ^ 0x1BD11BDAu;
  uint32_t x0 = c0 + ks0, x1 = c1 + ks1;
  const int r0[4] = {13, 15, 26, 6};
  const int r1[4] = {17, 29, 16, 24};
  for (int i = 0; i < 4; ++i) { x0 += x1; x1 = crotl(x1, r0[i]); x1 ^= x0; }
  x0 += ks1; x1 += ks2 + 1u;
  for (int i = 0; i < 4; ++i) { x0 += x1; x1 = crotl(x1, r1[i]); x1 ^= x0; }
  x0 += ks2; x1 += ks0 + 2u;
  for (int i = 0; i < 4; ++i) { x0 += x1; x1 = crotl(x1, r0[i]); x1 ^= x0; }
  x0 += ks0; x1 += ks1 + 3u;
  for (int i = 0; i < 4; ++i) { x0 += x1; x1 = crotl(x1, r1[i]); x1 ^= x0; }
  x0 += ks1; x1 += ks2 + 4u;
  for (int i = 0; i < 4; ++i) { x0 += x1; x1 = crotl(x1, r0[i]); x1 ^= x0; }
  x0 += ks2; x1 += ks0 + 5u;
  return K2{x0, x1};
}

struct KeyTable {
  uint32_t s0k[2];               // key for initial spins (k0)
  uint32_t sk[kSweeps][4];       // per sweep: k1a,k1b (accept), k2a,k2b (mask)
};

constexpr KeyTable make_keys() {
  KeyTable t{};
  K2 root{0u, 42u};              // jax.random.key(42) -> (hi=0, lo=42)
#if PARTITIONABLE
  K2 k0 = ctf(root.a, root.b, 0u, 0u);
  K2 kl = ctf(root.a, root.b, 0u, 1u);
#else
  K2 p0 = ctf(root.a, root.b, 0u, 2u);
  K2 p1 = ctf(root.a, root.b, 1u, 3u);
  K2 k0{p0.a, p1.a};
  K2 kl{p0.b, p1.b};
#endif
  t.s0k[0] = k0.a; t.s0k[1] = k0.b;
  K2 k = kl;
  for (int s = 0; s < kSweeps; ++s) {
#if PARTITIONABLE
    K2 kn = ctf(k.a, k.b, 0u, 0u);
    K2 k1 = ctf(k.a, k.b, 0u, 1u);
    K2 k2 = ctf(k.a, k.b, 0u, 2u);
#else
    K2 q0 = ctf(k.a, k.b, 0u, 3u);
    K2 q1 = ctf(k.a, k.b, 1u, 4u);
    K2 q2 = ctf(k.a, k.b, 2u, 5u);
    K2 kn{q0.a, q1.a};
    K2 k1{q2.a, q0.b};
    K2 k2{q1.b, q2.b};
#endif
    t.sk[s][0] = k1.a; t.sk[s][1] = k1.b;
    t.sk[s][2] = k2.a; t.sk[s][3] = k2.b;
    k = kn;
  }
  return t;
}

__constant__ KeyTable g_keys = make_keys();

__device__ __forceinline__ uint32_t rng_bits32(uint32_t ka, uint32_t kb, uint32_t m) {
#if PARTITIONABLE
  K2 r = ctf(ka, kb, 0u, m);
  return r.a ^ r.b;
#else
  constexpr uint32_t H = (uint32_t)(kB * kN / 2);
  uint32_t p = (m < H) ? m : (m - H);
  K2 r = ctf(ka, kb, p, p + H);
  return (m < H) ? r.a : r.b;
#endif
}

__device__ __forceinline__ float bits_to_uniform(uint32_t bits) {
  // jax: bitcast(bits >> 9 | 0x3f800000) - 1.0
  return __uint_as_float((bits >> 9) | 0x3f800000u) - 1.0f;
}

__global__ void prep_kernel(const float* __restrict__ gamma,
                            float* __restrict__ jsym,
                            float* __restrict__ betas) {
  int e = blockIdx.x * blockDim.x + threadIdx.x;   // 0..65535
  int i = e / kN, j = e % kN;
  float v = 0.0f;
  if (i < j) v = gamma[i * kN + j];
  else if (i > j) v = gamma[j * kN + i];
  jsym[e] = v;
  if (e < kSweeps) {
    double l0 = log(0.1), l1 = log(5.0);
    betas[e] = (float)exp(l0 + (l1 - l0) * (double)e / (double)(kSweeps - 1));
  }
}

// One VALU op per element: f32 fma with the f16 spin operand converted in-op.
// Conversion of +-1.0h to f32 is exact, then fp32 fma -> bit-identical to
// fmaf(+-1.0f, J, acc). op_sel picks lo/hi half of the packed u32.
#define FMIX_LO(a, w, j)                                                      \
  asm("v_fma_mix_f32 %0, %1, %2, %0 op_sel:[0,0,0] op_sel_hi:[1,0,0]"         \
      : "+v"(a) : "v"(w), "v"(j))
#define FMIX_HI(a, w, j)                                                      \
  asm("v_fma_mix_f32 %0, %1, %2, %0 op_sel:[1,0,0] op_sel_hi:[1,0,0]"         \
      : "+v"(a) : "v"(w), "v"(j))

// Exact matvec: acc[g] += sum_j s[g][j] * Jrow[j], j ascending, fp32 chain.
// Spins are fp16 (+-1.0h) in LDS: one ds_read_b128 = 8 spins.
// Software-pipelined A/B (chunk = 8 j's, 32 chunks), rolled 15-iter loop.
// NOTE: keep this exact kSamp=8 structure (round-3 codegen: pipelined,
// VGPR~68). kG=4 variants and full unroll both collapse the pipeline
// (rounds 4/5/6, VGPR 44-48, 2x slower).
__device__ __forceinline__ void matvec_h(const unsigned short* __restrict__ sh,
                                         const float4* __restrict__ jrow4,
                                         float (&acc)[kSamp]) {
#define LDSP(g, c) (*(const uint4*)(sh + (g) * kN + (c) * 8))
#define CONSUME(SP, J0, J1)                                                   \
  _Pragma("unroll")                                                           \
  for (int g = 0; g < kSamp; ++g) {                                           \
    FMIX_LO(acc[g], SP[g].x, J0.x); FMIX_HI(acc[g], SP[g].x, J0.y);           \
    FMIX_LO(acc[g], SP[g].y, J0.z); FMIX_HI(acc[g], SP[g].y, J0.w);           \
    FMIX_LO(acc[g], SP[g].z, J1.x); FMIX_HI(acc[g], SP[g].z, J1.y);           \
    FMIX_LO(acc[g], SP[g].w, J1.z); FMIX_HI(acc[g], SP[g].w, J1.w);           \
  }

  uint4 A[kSamp], B[kSamp];
  float4 jA0, jA1, jB0, jB1;
#pragma unroll
  for (int g = 0; g < kSamp; ++g) A[g] = LDSP(g, 0);
  jA0 = jrow4[0]; jA1 = jrow4[1];

#pragma unroll 1
  for (int k = 0; k < 15; ++k) {
    const int c = 2 * k;
    // body 1: prefetch chunk c+1 -> B, consume chunk c (A)
#pragma unroll
    for (int g = 0; g < kSamp; ++g) B[g] = LDSP(g, c + 1);
    jB0 = jrow4[2 * c + 2]; jB1 = jrow4[2 * c + 3];
    CONSUME(A, jA0, jA1)
    // body 2: prefetch chunk c+2 -> A, consume chunk c+1 (B)
#pragma unroll
    for (int g = 0; g < kSamp; ++g) A[g] = LDSP(g, c + 2);
    jA0 = jrow4[2 * c + 4]; jA1 = jrow4[2 * c + 5];
    CONSUME(B, jB0, jB1)
  }
  // tail: consume chunk 30 (A) while prefetching 31 -> B, then consume 31
#pragma unroll
  for (int g = 0; g < kSamp; ++g) B[g] = LDSP(g, 31);
  jB0 = jrow4[62]; jB1 = jrow4[63];
  CONSUME(A, jA0, jA1)
  CONSUME(B, jB0, jB1)
#undef LDSP
#undef CONSUME
}

__global__ __launch_bounds__(512) void anneal_kernel(
    const float* __restrict__ thetas, const float* __restrict__ jsym,
    const float* __restrict__ betas, float* __restrict__ out) {
  // fp16 spins (+1.0h=0x3C00, -1.0h=0xBC00), double-buffered: 8 KiB
  __shared__ __align__(16) unsigned short sh_h[2][kSamp][kN];
  // packed randoms w = ((b1>>9)<<1)|(b2>>31), one u32/site, dbuf: 16 KiB
  // (u1 = bitcast((w>>1)|0x3f800000)-1 bit-identical to bits_to_uniform(b1);
  //  mask passes <=> (w&1)==0 <=> u2<0.5 — validated in round 1)
  __shared__ __align__(16) uint32_t sh_rand[2][kSamp * kN];
  __shared__ float sh_red[kSamp][4];

  const int tid = threadIdx.x;
  const bool consumer = (tid < kN);    // waves 0-3 consume, 4-7 produce
  const int i = tid & (kN - 1);        // consumer: spin row; producer: tid2
  const int b0 = blockIdx.x * kSamp;   // first sample of this block
  const int lane = tid & 63;
  const int wid = (tid >> 6) & 3;

  float th[kSamp], sreg[kSamp];
  const float4* __restrict__ jrow4 = (const float4*)(jsym + i * kN);

  if (consumer) {
#pragma unroll
    for (int g = 0; g < kSamp; ++g) th[g] = thetas[(b0 + g) * kN + i];
    // s0 = where(bernoulli(k0, 0.5), 1, -1) ; bernoulli = uniform < 0.5
#pragma unroll
    for (int g = 0; g < kSamp; ++g) {
      uint32_t m = (uint32_t)((b0 + g) * kN + i);
      float u = bits_to_uniform(rng_bits32(g_keys.s0k[0], g_keys.s0k[1], m));
      sreg[g] = (u < 0.5f) ? 1.0f : -1.0f;
      sh_h[0][g][i] = (sreg[g] < 0.0f) ? (unsigned short)0xBC00
                                       : (unsigned short)0x3C00;
    }
  } else {
    // producer prologue: sweep-0 randoms into buffer 0
    const uint32_t k1a = g_keys.sk[0][0], k1b = g_keys.sk[0][1];
    const uint32_t k2a = g_keys.sk[0][2], k2b = g_keys.sk[0][3];
    const uint32_t mb = (uint32_t)(b0 * kN + i * 8);   // m is linear in site
    uint32_t wv[8];
#pragma unroll
    for (int q = 0; q < 8; ++q) {
      uint32_t b1 = rng_bits32(k1a, k1b, mb + q);
      uint32_t b2 = rng_bits32(k2a, k2b, mb + q);
      wv[q] = ((b1 >> 9) << 1) | (b2 >> 31);
    }
    uint4* dst = (uint4*)&sh_rand[0][i * 8];
    uint4 v0; v0.x = wv[0]; v0.y = wv[1]; v0.z = wv[2]; v0.w = wv[3];
    uint4 v1; v1.x = wv[4]; v1.y = wv[5]; v1.z = wv[6]; v1.w = wv[7];
    dst[0] = v0; dst[1] = v1;
  }
  __syncthreads();

  int cur = 0;
#pragma unroll 1
  for (int t = 0; t < kSweeps; ++t) {
    if (consumer) {
      const float beta = betas[t];
      // randoms for this sweep (produced last sweep / prologue)
      uint32_t w[kSamp];
      const uint32_t* __restrict__ rb = &sh_rand[t & 1][i];
#pragma unroll
      for (int g = 0; g < kSamp; ++g) w[g] = rb[g * kN];

      float acc[kSamp];
#pragma unroll
      for (int g = 0; g < kSamp; ++g) acc[g] = 0.0f;
      matvec_h(&sh_h[cur][0][0], jrow4, acc);

#pragma unroll
      for (int g = 0; g < kSamp; ++g) {
        float s = sreg[g];
        float local = th[g] + acc[g];
        float dE = -2.0f * s * local;  // exact: (-2*s) is a power of two
        float pr = expf(-beta * dE);
        float u1 = __uint_as_float((w[g] >> 1) | 0x3f800000u) - 1.0f;
        if ((u1 < pr) && ((w[g] & 1u) == 0u)) s = -s;   // accept & mask
        sreg[g] = s;
        sh_h[cur ^ 1][g][i] = (s < 0.0f) ? (unsigned short)0xBC00
                                         : (unsigned short)0x3C00;
      }
    } else if (t + 1 < kSweeps) {
      // producer: randoms for sweep t+1 into the other buffer, overlapped
      // with the consumers' LDS-bound matvec on this CU
      const uint32_t k1a = g_keys.sk[t + 1][0], k1b = g_keys.sk[t + 1][1];
      const uint32_t k2a = g_keys.sk[t + 1][2], k2b = g_keys.sk[t + 1][3];
      const uint32_t mb = (uint32_t)(b0 * kN + i * 8);
      uint32_t wv[8];
#pragma unroll
      for (int q = 0; q < 8; ++q) {
        uint32_t b1 = rng_bits32(k1a, k1b, mb + q);
        uint32_t b2 = rng_bits32(k2a, k2b, mb + q);
        wv[q] = ((b1 >> 9) << 1) | (b2 >> 31);
      }
      uint4* dst = (uint4*)&sh_rand[(t + 1) & 1][i * 8];
      uint4 v0; v0.x = wv[0]; v0.y = wv[1]; v0.z = wv[2]; v0.w = wv[3];
      uint4 v1; v1.x = wv[4]; v1.y = wv[5]; v1.z = wv[6]; v1.w = wv[7];
      dst[0] = v0; dst[1] = v1;
    }
    __syncthreads();   // spins(nxt) + randoms(t+1) visible; roles stay in step
    cur ^= 1;
  }

  // E_b = sum_i s_i*theta_i + 0.5 * sum_i s_i * (Jsym s)_i  (consumers only)
  if (consumer) {
    float acc[kSamp];
#pragma unroll
    for (int g = 0; g < kSamp; ++g) acc[g] = 0.0f;
    matvec_h(&sh_h[cur][0][0], jrow4, acc);

#pragma unroll
    for (int g = 0; g < kSamp; ++g) {
      float v = sreg[g] * th[g] + 0.5f * (sreg[g] * acc[g]);
#pragma unroll
      for (int off = 32; off > 0; off >>= 1) v += __shfl_down(v, off);
      if (lane == 0) sh_red[g][wid] = v;
    }
  }
  __syncthreads();
  if (tid < kSamp) {
    out[b0 + tid] = sh_red[tid][0] + sh_red[tid][1] + sh_red[tid][2] + sh_red[tid][3];
  }
}

}  // namespace

extern "C" void kernel_launch(void* const* d_in, const int* in_sizes, int n_in,
                              void* d_out, int out_size, void* d_ws, size_t ws_size,
                              hipStream_t stream) {
  const float* thetas = (const float*)d_in[0];   // [4096, 256]
  const float* gamma  = (const float*)d_in[1];   // [256, 256]
  float* jsym  = (float*)d_ws;                              // 256 KiB
  float* betas = (float*)((char*)d_ws + kN * kN * sizeof(float));

  hipLaunchKernelGGL(prep_kernel, dim3(kN), dim3(kN), 0, stream, gamma, jsym, betas);
  hipLaunchKernelGGL(anneal_kernel, dim3(kBlocks), dim3(512), 0, stream,
                     thetas, jsym, betas, (float*)d_out);
}